// Round 1
// baseline (139.576 us; speedup 1.0000x reference)
//
#include <hip/hip_runtime.h>

// casConv2d: B=1, C=128, H=W=32, OC=128, K=3, pad=1, stride=1
// L = 32*32 = 1024, CKK = 1152, 36 real chunks of 32 taps (front pad chunk == 0)
#define CKK_   1152
#define L_     1024
#define QMAX_  255.0f

// Chunked conv-as-GEMM. grid = (32 l-tiles [one output row each], 9 chunk-groups of 4),
// block = 256 threads, each thread owns a 4(oc) x 4(l) microtile.
// QUANT=false: accumulate raw sums over the 4 chunks, atomicAdd into conv buffer.
// QUANT=true : fake-quantize each 32-tap chunk sum with (scale,zp), atomicAdd deq-sums into out.
template <bool QUANT>
__global__ __launch_bounds__(256) void cas_gemm(
    const float* __restrict__ x,      // [128][32][32]
    const float* __restrict__ w,      // [128][1152]  (oc, c*9+kh*3+kw)
    float* __restrict__ out,          // [128][1024]  (atomicAdd target, pre-zeroed)
    const float* __restrict__ scale,  // [1024] (QUANT only)
    const float* __restrict__ zp)     // [1024] (QUANT only)
{
    __shared__ __align__(16) float Ws[32][132];  // k-major, pad 132: b128 reads conflict-free
    __shared__ __align__(16) float Xs[32][32];

    const int t  = threadIdx.x;
    const int bx = blockIdx.x;        // output row oh = bx; l0 = bx*32
    const int j0 = blockIdx.y * 4;    // first chunk of this k-group
    const int lb = (t & 7) * 4;       // l (== ow) base, 0..28
    const int ob = (t >> 3) * 4;      // oc base, 0..124

    float acc[4][4];                  // running chunk (or group) sums
    float sum[4][4];                  // deq accumulator (QUANT)
    float sc[4], zv[4];
#pragma unroll
    for (int i = 0; i < 4; i++)
#pragma unroll
        for (int q = 0; q < 4; q++) { acc[i][q] = 0.f; sum[i][q] = 0.f; }

    if (QUANT) {
#pragma unroll
        for (int q = 0; q < 4; q++) {
            sc[q] = scale[bx * 32 + lb + q];
            zv[q] = zp[bx * 32 + lb + q];
        }
    }

    for (int jj = 0; jj < 4; jj++) {
        const int j = j0 + jj;  // chunk index 0..35, taps d = j*32 .. j*32+31

        // Stage W chunk: 128 oc x 32 k, k-major in LDS. Lanes: consecutive k, same oc
        // -> coalesced 128B global segments.
#pragma unroll
        for (int e = t; e < 4096; e += 256) {
            const int oc = e >> 5, k = e & 31;
            Ws[k][oc] = w[oc * CKK_ + j * 32 + k];
        }
        // Stage X chunk: 32 k x 32 l (l == ow since one row per block). Lanes:
        // consecutive li -> consecutive ix -> coalesced (with pad predication).
#pragma unroll
        for (int e = t; e < 1024; e += 256) {
            const int k = e >> 5, li = e & 31;
            const int d = j * 32 + k;
            const int c = d / 9, rem = d - c * 9;
            const int kh = rem / 3, kw = rem - kh * 3;
            const int iy = bx + kh - 1, ix = li + kw - 1;
            float v = 0.f;
            if ((unsigned)iy < 32u && (unsigned)ix < 32u)
                v = x[c * 1024 + iy * 32 + ix];
            Xs[k][li] = v;
        }
        __syncthreads();

#pragma unroll
        for (int k = 0; k < 32; k++) {
            const float4 xv = *(const float4*)&Xs[k][lb];
            const float4 wv = *(const float4*)&Ws[k][ob];
            acc[0][0] += wv.x * xv.x; acc[0][1] += wv.x * xv.y; acc[0][2] += wv.x * xv.z; acc[0][3] += wv.x * xv.w;
            acc[1][0] += wv.y * xv.x; acc[1][1] += wv.y * xv.y; acc[1][2] += wv.y * xv.z; acc[1][3] += wv.y * xv.w;
            acc[2][0] += wv.z * xv.x; acc[2][1] += wv.z * xv.y; acc[2][2] += wv.z * xv.z; acc[2][3] += wv.z * xv.w;
            acc[3][0] += wv.w * xv.x; acc[3][1] += wv.w * xv.y; acc[3][2] += wv.w * xv.z; acc[3][3] += wv.w * xv.w;
        }

        if (QUANT) {
            // per-chunk fake-quant (round-half-even == jnp.round), then reset chunk acc
#pragma unroll
            for (int i = 0; i < 4; i++)
#pragma unroll
                for (int q = 0; q < 4; q++) {
                    const float a  = acc[i][q];
                    float       qn = rintf(a / sc[q]) + zv[q];
                    qn = fminf(fmaxf(qn, 0.f), QMAX_);
                    sum[i][q] += (qn - zv[q]) * sc[q];
                    acc[i][q] = 0.f;
                }
        }
        __syncthreads();
    }

#pragma unroll
    for (int i = 0; i < 4; i++)
#pragma unroll
        for (int q = 0; q < 4; q++) {
            const float v = QUANT ? sum[i][q] : acc[i][q];
            atomicAdd(&out[(ob + i) * L_ + bx * 32 + lb + q], v);
        }
}

// Per-pixel min/max over 128 OC of (conv + bias) -> scale, zp. 64 blocks x 256 thr,
// 16 pixels per block, 16 oc-groups of 8 per pixel, LDS tree for the cross-group reduce.
__global__ __launch_bounds__(256) void cas_minmax(
    const float* __restrict__ conv,   // [128][1024] raw conv sums (no bias)
    const float* __restrict__ bias,   // [128]
    float* __restrict__ scale,        // [1024]
    float* __restrict__ zp)           // [1024]
{
    __shared__ float smn[16][17], smx[16][17];
    const int t  = threadIdx.x;
    const int li = t & 15, g = t >> 4;
    const int l  = blockIdx.x * 16 + li;

    float mn = INFINITY, mx = -INFINITY;
#pragma unroll
    for (int i = 0; i < 8; i++) {
        const int oc = g * 8 + i;
        const float v = conv[oc * L_ + l] + bias[oc];
        mn = fminf(mn, v);
        mx = fmaxf(mx, v);
    }
    smn[g][li] = mn;
    smx[g][li] = mx;
    __syncthreads();

    if (t < 16) {
        const int l2 = blockIdx.x * 16 + t;
        float amn = smn[0][t], amx = smx[0][t];
#pragma unroll
        for (int g2 = 1; g2 < 16; g2++) {
            amn = fminf(amn, smn[g2][t]);
            amx = fmaxf(amx, smx[g2][t]);
        }
        const float s = (amx - amn) / QMAX_;
        float z = -amn / s;
        z = fmaxf(z, 0.f);          // fmaxf(NaN,0)=0 -> matches jnp where(isnan, 0)
        z = fminf(z, QMAX_);
        z = truncf(z);              // .int() truncation
        scale[l2] = s;
        zp[l2]    = z;
    }
}

extern "C" void kernel_launch(void* const* d_in, const int* in_sizes, int n_in,
                              void* d_out, int out_size, void* d_ws, size_t ws_size,
                              hipStream_t stream) {
    const float* x    = (const float*)d_in[0];  // 128*32*32
    const float* w    = (const float*)d_in[1];  // 128*1152
    const float* bias = (const float*)d_in[2];  // 128
    float* out = (float*)d_out;                 // 128*1024

    float* conv  = (float*)d_ws;                // 131072 floats
    float* scale = conv + 131072;               // 1024
    float* zpv   = scale + 1024;                // 1024

    hipMemsetAsync(conv, 0, 131072 * sizeof(float), stream);
    hipMemsetAsync(out, 0, (size_t)out_size * sizeof(float), stream);

    dim3 grid(32, 9), block(256);
    cas_gemm<false><<<grid, block, 0, stream>>>(x, w, conv, nullptr, nullptr);
    cas_minmax<<<64, 256, 0, stream>>>(conv, bias, scale, zpv);
    cas_gemm<true><<<grid, block, 0, stream>>>(x, w, out, scale, zpv);
}

// Round 2
// 139.408 us; speedup vs baseline: 1.0012x; 1.0012x over previous
//
#include <hip/hip_runtime.h>

// casConv2d: B=1, C=128, H=W=32, OC=128, K=3, pad=1, stride=1
// L = 1024, CKK = 1152 -> 36 real 32-tap chunks (front pad chunk contributes 0).
// Round-2 structure: NO atomics (round-1 showed 18 MB of atomic write-through at
// ~450 GB/s dominating both GEMM dispatches). Split-k GEMM writes partial planes
// with plain stores; a separate coalesced plane_sum reduces them.
#define CKK_   1152
#define L_     1024
#define QMAX_  255.0f

// Chunked conv-as-GEMM. grid = (32 output rows, P=36/CH chunk-groups), block=256,
// each thread owns a 4(oc) x 4(l) microtile. Writes its partial plane with plain
// float4 stores (raw sums if !QUANT, per-chunk fake-quant deq sums if QUANT).
template <int CH, bool QUANT>
__global__ __launch_bounds__(256) void cas_gemm(
    const float* __restrict__ x,      // [128][32][32]
    const float* __restrict__ w,      // [128][1152]
    float* __restrict__ planes,       // [P][128][1024]; this block writes plane blockIdx.y
    const float* __restrict__ scale,  // [1024] (QUANT)
    const float* __restrict__ zp,     // [1024] (QUANT)
    const float* __restrict__ inv)    // [1024] (QUANT) 1/scale
{
    __shared__ __align__(16) float Ws[32][132];  // k-major, pad 132: b128 conflict-free
    __shared__ __align__(16) float Xs[32][32];

    const int t  = threadIdx.x;
    const int bx = blockIdx.x;        // output row; l0 = bx*32
    const int p  = blockIdx.y;        // chunk-group / plane index
    const int lb = (t & 7) * 4;       // l (== ow) base
    const int ob = (t >> 3) * 4;      // oc base

    float acc[4][4];                  // chunk (or group) running sums
    float sum[4][4];                  // deq accumulator (QUANT)
    float sc[4], zv[4], iv[4];
#pragma unroll
    for (int i = 0; i < 4; i++)
#pragma unroll
        for (int q = 0; q < 4; q++) { acc[i][q] = 0.f; sum[i][q] = 0.f; }

    if (QUANT) {
#pragma unroll
        for (int q = 0; q < 4; q++) {
            sc[q] = scale[bx * 32 + lb + q];
            zv[q] = zp[bx * 32 + lb + q];
            iv[q] = inv[bx * 32 + lb + q];
        }
    }

    for (int jj = 0; jj < CH; jj++) {
        const int j = p * CH + jj;    // chunk 0..35, taps d = j*32 .. j*32+31

        // Stage W chunk: 128 oc x 32 k, k-major. Coalesced 128B segments.
#pragma unroll
        for (int e = t; e < 4096; e += 256) {
            const int oc = e >> 5, k = e & 31;
            Ws[k][oc] = w[oc * CKK_ + j * 32 + k];
        }
        // Stage X chunk: 32 k x 32 l (l == ow; one output row per block).
#pragma unroll
        for (int e = t; e < 1024; e += 256) {
            const int k = e >> 5, li = e & 31;
            const int d = j * 32 + k;
            const int c = d / 9, rem = d - c * 9;
            const int kh = rem / 3, kw = rem - kh * 3;
            const int iy = bx + kh - 1, ix = li + kw - 1;
            float v = 0.f;
            if ((unsigned)iy < 32u && (unsigned)ix < 32u)
                v = x[c * 1024 + iy * 32 + ix];
            Xs[k][li] = v;
        }
        __syncthreads();

#pragma unroll
        for (int k = 0; k < 32; k++) {
            const float4 xv = *(const float4*)&Xs[k][lb];
            const float4 wv = *(const float4*)&Ws[k][ob];
            acc[0][0] += wv.x * xv.x; acc[0][1] += wv.x * xv.y; acc[0][2] += wv.x * xv.z; acc[0][3] += wv.x * xv.w;
            acc[1][0] += wv.y * xv.x; acc[1][1] += wv.y * xv.y; acc[1][2] += wv.y * xv.z; acc[1][3] += wv.y * xv.w;
            acc[2][0] += wv.z * xv.x; acc[2][1] += wv.z * xv.y; acc[2][2] += wv.z * xv.z; acc[2][3] += wv.z * xv.w;
            acc[3][0] += wv.w * xv.x; acc[3][1] += wv.w * xv.y; acc[3][2] += wv.w * xv.z; acc[3][3] += wv.w * xv.w;
        }

        if (QUANT) {
            // per-chunk fake-quant (rintf == round-half-even == jnp.round)
#pragma unroll
            for (int i = 0; i < 4; i++)
#pragma unroll
                for (int q = 0; q < 4; q++) {
                    const float a  = acc[i][q];
                    float       qn = rintf(a * iv[q]) + zv[q];
                    qn = fminf(fmaxf(qn, 0.f), QMAX_);
                    sum[i][q] += (qn - zv[q]) * sc[q];
                    acc[i][q] = 0.f;
                }
        }
        __syncthreads();
    }

    float* dst = planes + ((size_t)p << 17);  // plane stride 128*1024
#pragma unroll
    for (int i = 0; i < 4; i++) {
        float4 v;
        if (QUANT) v = make_float4(sum[i][0], sum[i][1], sum[i][2], sum[i][3]);
        else       v = make_float4(acc[i][0], acc[i][1], acc[i][2], acc[i][3]);
        *(float4*)&dst[(ob + i) * L_ + bx * 32 + lb] = v;
    }
}

// out[e] = sum_p planes[p][e], e < 131072. Perfectly coalesced, 512 blocks.
__global__ __launch_bounds__(256) void plane_sum(
    const float* __restrict__ planes, float* __restrict__ out, int P)
{
    const int e = blockIdx.x * 256 + threadIdx.x;
    float s = planes[e];
    for (int p = 1; p < P; p++) s += planes[p * 131072 + e];
    out[e] = s;
}

// Per-pixel min/max over 128 OC of (conv + bias) -> scale, zp, inv_scale.
__global__ __launch_bounds__(256) void cas_minmax(
    const float* __restrict__ conv,   // [128][1024]
    const float* __restrict__ bias,   // [128]
    float* __restrict__ scale,        // [1024]
    float* __restrict__ zp,           // [1024]
    float* __restrict__ inv)          // [1024]
{
    __shared__ float smn[16][17], smx[16][17];
    const int t  = threadIdx.x;
    const int li = t & 15, g = t >> 4;
    const int l  = blockIdx.x * 16 + li;

    float mn = INFINITY, mx = -INFINITY;
#pragma unroll
    for (int i = 0; i < 8; i++) {
        const int oc = g * 8 + i;
        const float v = conv[oc * L_ + l] + bias[oc];
        mn = fminf(mn, v);
        mx = fmaxf(mx, v);
    }
    smn[g][li] = mn;
    smx[g][li] = mx;
    __syncthreads();

    if (t < 16) {
        const int l2 = blockIdx.x * 16 + t;
        float amn = smn[0][t], amx = smx[0][t];
#pragma unroll
        for (int g2 = 1; g2 < 16; g2++) {
            amn = fminf(amn, smn[g2][t]);
            amx = fmaxf(amx, smx[g2][t]);
        }
        const float s = (amx - amn) / QMAX_;
        float z = -amn / s;
        z = fmaxf(z, 0.f);          // fmaxf(NaN,0)=0 -> matches where(isnan, 0)
        z = fminf(z, QMAX_);
        z = truncf(z);
        scale[l2] = s;
        zp[l2]    = z;
        inv[l2]   = 1.0f / s;
    }
}

template <int CH>
static void run_path(const float* x, const float* w, const float* bias,
                     float* out, float* ws, hipStream_t stream)
{
    constexpr int P = 36 / CH;
    float* planes = ws;
    float* conv   = ws + (size_t)P * 131072;
    float* scale  = conv + 131072;
    float* zpv    = scale + 1024;
    float* inv    = zpv + 1024;
    dim3 g(32, P), b(256);
    cas_gemm<CH, false><<<g, b, 0, stream>>>(x, w, planes, nullptr, nullptr, nullptr);
    plane_sum<<<512, 256, 0, stream>>>(planes, conv, P);
    cas_minmax<<<64, 256, 0, stream>>>(conv, bias, scale, zpv, inv);
    cas_gemm<CH, true><<<g, b, 0, stream>>>(x, w, planes, scale, zpv, inv);
    plane_sum<<<512, 256, 0, stream>>>(planes, out, P);
}

// Floor path (tiny ws): single chunk-group of 36, partials ARE the outputs.
static void run_floor(const float* x, const float* w, const float* bias,
                      float* out, float* ws, hipStream_t stream)
{
    float* conv  = ws;            // 131072
    float* scale = conv + 131072;
    float* zpv   = scale + 1024;
    float* inv   = zpv + 1024;
    dim3 g(32, 1), b(256);
    cas_gemm<36, false><<<g, b, 0, stream>>>(x, w, conv, nullptr, nullptr, nullptr);
    cas_minmax<<<64, 256, 0, stream>>>(conv, bias, scale, zpv, inv);
    cas_gemm<36, true><<<g, b, 0, stream>>>(x, w, out, scale, zpv, inv);
}

extern "C" void kernel_launch(void* const* d_in, const int* in_sizes, int n_in,
                              void* d_out, int out_size, void* d_ws, size_t ws_size,
                              hipStream_t stream) {
    const float* x    = (const float*)d_in[0];  // 128*32*32
    const float* w    = (const float*)d_in[1];  // 128*1152
    const float* bias = (const float*)d_in[2];  // 128
    float* out = (float*)d_out;                 // 128*1024
    float* ws  = (float*)d_ws;

    auto fits = [&](int P) {
        return ws_size >= (size_t)(P + 1) * 131072 * 4 + 3 * 1024 * 4;
    };
    if      (fits(18)) run_path<2>(x, w, bias, out, ws, stream);  // ~10 MB ws
    else if (fits(9))  run_path<4>(x, w, bias, out, ws, stream);  // ~5.3 MB
    else if (fits(4))  run_path<9>(x, w, bias, out, ws, stream);  // ~2.6 MB
    else               run_floor(x, w, bias, out, ws, stream);    // ~537 KB
}

// Round 3
// 135.150 us; speedup vs baseline: 1.0328x; 1.0315x over previous
//
#include <hip/hip_runtime.h>

// casConv2d: B=1, C=128, H=W=32, OC=128, K=3, pad=1, stride=1.
// L = 1024, CKK = 1152 -> 36 real 32-tap chunks (reference's front pad chunk == 0).
//
// Round-3 structure: rounds 1-2 proved the bottleneck is NOT writes/atomics but
// the per-chunk {global->LDS->barrier} staging (waves stalled ~30k cyc on
// serialized load latency at ~2 blocks/CU). This version has NO LDS and NO
// __syncthreads in the GEMM: x-taps live in per-lane VGPRs (read from a
// pre-padded xpad, so tap address = scalar_off + lane_off with zero VALU and
// no bounds checks), and W rows are wave-uniform -> SGPRs via s_load (scalar
// pipe + constant cache). Waves run fully independently.
#define L_     1024
#define CKK_   1152
#define QMAX_  255.0f
#define XPAD_N (128 * 1156)   // [128][34][34]

// xpad[c][1+y][1+x] = x[c][y][x], zero border. Runs every launch (ws re-poisoned).
__global__ __launch_bounds__(256) void pad_x(const float* __restrict__ x,
                                             float* __restrict__ xpad) {
    const int i = blockIdx.x * 256 + threadIdx.x;
    if (i >= XPAD_N) return;
    const int c = i / 1156, rem = i - c * 1156;
    const int iy = rem / 34, ix = rem - iy * 34;
    float v = 0.f;
    if (iy >= 1 && iy <= 32 && ix >= 1 && ix <= 32)
        v = x[c * 1024 + (iy - 1) * 32 + (ix - 1)];
    xpad[i] = v;
}

// Tile: 16 oc x 256 l x CH chunks per block. grid = (8 ocg, 4 lg, 36/CH ksplits).
// QUANT=false: raw sums over CH chunks -> plane.  QUANT=true: per-chunk
// fake-quant (rintf == round-half-even), deq sums -> plane.
template <int CH, bool QUANT>
__global__ __launch_bounds__(256) void cas_gemm(
    const float* __restrict__ xpad,   // [128][34][34]
    const float* __restrict__ w,      // [128][1152]
    float* __restrict__ planes,       // [P][128][1024]
    const float* __restrict__ scale,  // [1024] (QUANT)
    const float* __restrict__ zp,     // [1024] (QUANT)
    const float* __restrict__ inv)    // [1024] (QUANT) 1/scale
{
    const int t      = threadIdx.x;
    const int ocBase = blockIdx.x * 16;
    const int l      = blockIdx.y * 256 + t;       // output pixel, lanes contiguous
    const int p      = blockIdx.z;                  // k-split / plane index
    const int oh     = l >> 5, ow = l & 31;
    const int lane_off = oh * 34 + ow;              // padded-x lane term (kh=kw=0 corner)

    float sc = 0.f, zv = 0.f, iv = 0.f;
    if (QUANT) { sc = scale[l]; zv = zp[l]; iv = inv[l]; }

    float acc[16];
#pragma unroll
    for (int oc = 0; oc < 16; oc++) acc[oc] = 0.f;

    for (int jj = 0; jj < CH; jj++) {
        const int d0 = (p * CH + jj) * 32;          // first tap of this chunk (uniform)

        // x-column for this pixel: 32 independent loads, scalar tap offsets.
        float xv[32];
#pragma unroll
        for (int dd = 0; dd < 32; dd++) {
            const int d  = d0 + dd;                 // uniform scalar
            const int c  = d / 9;
            const int r  = d - 9 * c;
            const int kh = r / 3;
            const int kw = r - 3 * kh;
            xv[dd] = xpad[c * 1156 + kh * 34 + kw + lane_off];
        }

#pragma unroll
        for (int oc = 0; oc < 16; oc++) {
            // wave-uniform address -> s_load into SGPRs, FMA reads SGPR operand
            const float4* wp = (const float4*)(w + (ocBase + oc) * CKK_ + d0);
            float pa = 0.f, pb = 0.f;               // 2 chains: hide FMA latency
#pragma unroll
            for (int k4 = 0; k4 < 4; k4++) {
                const float4 wv = wp[k4];
                pa = fmaf(wv.x, xv[4 * k4 + 0], pa);
                pa = fmaf(wv.y, xv[4 * k4 + 1], pa);
                pa = fmaf(wv.z, xv[4 * k4 + 2], pa);
                pa = fmaf(wv.w, xv[4 * k4 + 3], pa);
            }
#pragma unroll
            for (int k4 = 4; k4 < 8; k4++) {
                const float4 wv = wp[k4];
                pb = fmaf(wv.x, xv[4 * k4 + 0], pb);
                pb = fmaf(wv.y, xv[4 * k4 + 1], pb);
                pb = fmaf(wv.z, xv[4 * k4 + 2], pb);
                pb = fmaf(wv.w, xv[4 * k4 + 3], pb);
            }
            const float s2 = pa + pb;               // chunk partial sum
            if (QUANT) {
                float qn = rintf(s2 * iv) + zv;
                qn = fminf(fmaxf(qn, 0.f), QMAX_);
                acc[oc] += (qn - zv) * sc;
            } else {
                acc[oc] += s2;
            }
        }
    }

    float* dst = planes + (size_t)p * 131072;
#pragma unroll
    for (int oc = 0; oc < 16; oc++)
        dst[(ocBase + oc) * L_ + l] = acc[oc];      // coalesced dword stores
}

// out[e] = sum_p planes[p][e]. 512 blocks, perfectly coalesced.
__global__ __launch_bounds__(256) void plane_sum(
    const float* __restrict__ planes, float* __restrict__ out, int P)
{
    const int e = blockIdx.x * 256 + threadIdx.x;
    float s = planes[e];
    for (int p = 1; p < P; p++) s += planes[p * 131072 + e];
    out[e] = s;
}

// Per-pixel min/max over 128 OC of (conv + bias) -> scale, zp, inv.
__global__ __launch_bounds__(256) void cas_minmax(
    const float* __restrict__ conv,   // [128][1024]
    const float* __restrict__ bias,   // [128]
    float* __restrict__ scale, float* __restrict__ zp, float* __restrict__ inv)
{
    __shared__ float smn[16][17], smx[16][17];
    const int t  = threadIdx.x;
    const int li = t & 15, g = t >> 4;
    const int l  = blockIdx.x * 16 + li;

    float mn = INFINITY, mx = -INFINITY;
#pragma unroll
    for (int i = 0; i < 8; i++) {
        const int oc = g * 8 + i;
        const float v = conv[oc * L_ + l] + bias[oc];
        mn = fminf(mn, v);
        mx = fmaxf(mx, v);
    }
    smn[g][li] = mn;
    smx[g][li] = mx;
    __syncthreads();

    if (t < 16) {
        const int l2 = blockIdx.x * 16 + t;
        float amn = smn[0][t], amx = smx[0][t];
#pragma unroll
        for (int g2 = 1; g2 < 16; g2++) {
            amn = fminf(amn, smn[g2][t]);
            amx = fmaxf(amx, smx[g2][t]);
        }
        const float s = (amx - amn) / QMAX_;
        float z = -amn / s;
        z = fmaxf(z, 0.f);          // fmaxf(NaN,0)=0 matches where(isnan, 0)
        z = fminf(z, QMAX_);
        z = truncf(z);
        scale[l2] = s;
        zp[l2]    = z;
        inv[l2]   = 1.0f / s;
    }
}

template <int CH>
static void run_path(const float* x, const float* w, const float* bias,
                     float* out, float* ws, hipStream_t stream)
{
    constexpr int P = 36 / CH;
    float* planes = ws;
    float* conv   = ws + (size_t)P * 131072;
    float* scale  = conv + 131072;
    float* zpv    = scale + 1024;
    float* inv    = zpv + 1024;
    float* xpad   = inv + 1024;

    pad_x<<<(XPAD_N + 255) / 256, 256, 0, stream>>>(x, xpad);

    dim3 g(8, 4, P), b(256);
    if (P == 1) {
        // direct-write fallback: plane IS conv/out
        cas_gemm<CH, false><<<g, b, 0, stream>>>(xpad, w, conv, nullptr, nullptr, nullptr);
        cas_minmax<<<64, 256, 0, stream>>>(conv, bias, scale, zpv, inv);
        cas_gemm<CH, true><<<g, b, 0, stream>>>(xpad, w, out, scale, zpv, inv);
    } else {
        cas_gemm<CH, false><<<g, b, 0, stream>>>(xpad, w, planes, nullptr, nullptr, nullptr);
        plane_sum<<<512, 256, 0, stream>>>(planes, conv, P);
        cas_minmax<<<64, 256, 0, stream>>>(conv, bias, scale, zpv, inv);
        cas_gemm<CH, true><<<g, b, 0, stream>>>(xpad, w, planes, scale, zpv, inv);
        plane_sum<<<512, 256, 0, stream>>>(planes, out, P);
    }
}

extern "C" void kernel_launch(void* const* d_in, const int* in_sizes, int n_in,
                              void* d_out, int out_size, void* d_ws, size_t ws_size,
                              hipStream_t stream) {
    const float* x    = (const float*)d_in[0];  // 128*32*32
    const float* w    = (const float*)d_in[1];  // 128*1152
    const float* bias = (const float*)d_in[2];  // 128
    float* out = (float*)d_out;                 // 128*1024
    float* ws  = (float*)d_ws;

    auto fits = [&](int P) {
        return ws_size >= ((size_t)(P + 1) * 131072 + 3 * 1024 + XPAD_N) * 4;
    };
    if      (fits(12)) run_path<3>(x, w, bias, out, ws, stream);   // ~7.4 MB ws
    else if (fits(4))  run_path<9>(x, w, bias, out, ws, stream);   // ~3.2 MB
    else               run_path<36>(x, w, bias, out, ws, stream);  // ~1.7 MB, direct
}

// Round 4
// 110.400 us; speedup vs baseline: 1.2643x; 1.2242x over previous
//
#include <hip/hip_runtime.h>

// casConv2d: B=1, C=128, H=W=32, OC=128, K=3, pad=1, stride=1.
// L = 1024, CKK = 1152 = 36 exact 32-tap chunks (reference front-pad chunk == 0).
//
// Round-4 structure. Rounds 1-3 proved: (a) epilogue writes/atomics irrelevant,
// (b) the GEMM was latency-bound at 1.5 waves/SIMD (grid too small), and
// (c) we were doing the 302-MFLOP GEMM twice. Fix both:
//   1. ONE gemm pass materializes chunk sums [36][128][1024] (18 MB, L2-scale).
//   2. min/max + fake-quant become streaming elementwise passes over the planes.
//   3. GEMM grid = 2304 blocks (36 waves/CU) so load stalls overlap across waves.
#define L_     1024
#define CKK_   1152
#define QMAX_  255.0f
#define XPAD_N (128 * 1156)   // [128][34][34]
#define NCH    36
#define PLANE_ 131072         // 128*1024

// xpad[c][1+y][1+x] = x[c][y][x], zero border (re-done every launch: ws poisoned).
__global__ __launch_bounds__(256) void pad_x(const float* __restrict__ x,
                                             float* __restrict__ xpad) {
    const int i = blockIdx.x * 256 + threadIdx.x;
    if (i >= XPAD_N) return;
    const int c = i / 1156, rem = i - c * 1156;
    const int iy = rem / 34, ix = rem - iy * 34;
    float v = 0.f;
    if (iy >= 1 && iy <= 32 && ix >= 1 && ix <= 32)
        v = x[c * 1024 + (iy - 1) * 32 + (ix - 1)];
    xpad[i] = v;
}

// One 32-tap chunk sum per (oc,l). Tile: 8 oc x 256 l x 1 chunk.
// grid = (16 ocg, 4 lg, 36 chunks) = 2304 blocks = 9216 waves = 36 waves/CU.
// Tap/channel decode is wave-uniform -> scalar pipe; x address = sgpr + lane_off;
// W rows are wave-uniform -> s_load into SGPRs.
__global__ __launch_bounds__(256) void gemm_chunks(
    const float* __restrict__ xpad,   // [128][34][34]
    const float* __restrict__ w,      // [128][1152]
    float* __restrict__ planes)       // [36][128][1024]
{
    const int t        = threadIdx.x;
    const int ocBase   = blockIdx.x * 8;
    const int l        = blockIdx.y * 256 + t;
    const int j        = blockIdx.z;
    const int oh       = l >> 5, ow = l & 31;
    const int lane_off = oh * 34 + ow;
    const int d0       = j * 32;

    // x-column: 32 independent loads, uniform tap offsets (scalarized decode).
    float xv[32];
#pragma unroll
    for (int dd = 0; dd < 32; dd++) {
        const int d  = d0 + dd;
        const int c  = d / 9;
        const int r  = d - 9 * c;
        const int kh = r / 3;
        const int kw = r - 3 * kh;
        xv[dd] = xpad[c * 1156 + kh * 34 + kw + lane_off];
    }

    float acc[8];
#pragma unroll
    for (int oc = 0; oc < 8; oc++) {
        const float4* wp = (const float4*)(w + (ocBase + oc) * CKK_ + d0);
        float pa = 0.f, pb = 0.f;     // two chains hide FMA latency
#pragma unroll
        for (int k4 = 0; k4 < 4; k4++) {
            const float4 wv = wp[k4];
            pa = fmaf(wv.x, xv[4 * k4 + 0], pa);
            pa = fmaf(wv.y, xv[4 * k4 + 1], pa);
            pa = fmaf(wv.z, xv[4 * k4 + 2], pa);
            pa = fmaf(wv.w, xv[4 * k4 + 3], pa);
        }
#pragma unroll
        for (int k4 = 4; k4 < 8; k4++) {
            const float4 wv = wp[k4];
            pb = fmaf(wv.x, xv[4 * k4 + 0], pb);
            pb = fmaf(wv.y, xv[4 * k4 + 1], pb);
            pb = fmaf(wv.z, xv[4 * k4 + 2], pb);
            pb = fmaf(wv.w, xv[4 * k4 + 3], pb);
        }
        acc[oc] = pa + pb;
    }

    float* dst = planes + (size_t)j * PLANE_;
#pragma unroll
    for (int oc = 0; oc < 8; oc++)
        dst[(ocBase + oc) * L_ + l] = acc[oc];   // coalesced dword stores
}

// Per-pixel min/max over 128 oc of (sum_j chunks + bias) -> scale, zp, inv.
// 64 blocks x 256 thr; 16 pixels/block; 16 oc-groups of 8; LDS cross-group reduce.
__global__ __launch_bounds__(256) void minmax_planes(
    const float* __restrict__ planes, const float* __restrict__ bias,
    float* __restrict__ scale, float* __restrict__ zp, float* __restrict__ inv)
{
    __shared__ float smn[16][17], smx[16][17];
    const int t  = threadIdx.x;
    const int li = t & 15, g = t >> 4;
    const int l  = blockIdx.x * 16 + li;

    float mn = INFINITY, mx = -INFINITY;
#pragma unroll
    for (int i = 0; i < 8; i++) {
        const int oc = g * 8 + i;
        const float* p = planes + oc * L_ + l;
        float s = 0.f;
#pragma unroll 4
        for (int j = 0; j < NCH; j++) s += p[j * PLANE_];
        const float v = s + bias[oc];
        mn = fminf(mn, v);
        mx = fmaxf(mx, v);
    }
    smn[g][li] = mn;
    smx[g][li] = mx;
    __syncthreads();

    if (t < 16) {
        const int l2 = blockIdx.x * 16 + t;
        float amn = smn[0][t], amx = smx[0][t];
#pragma unroll
        for (int g2 = 1; g2 < 16; g2++) {
            amn = fminf(amn, smn[g2][t]);
            amx = fmaxf(amx, smx[g2][t]);
        }
        const float s = (amx - amn) / QMAX_;
        float z = -amn / s;
        z = fmaxf(z, 0.f);          // fmaxf(NaN,0)=0 matches where(isnan, 0)
        z = fminf(z, QMAX_);
        z = truncf(z);
        scale[l2] = s;
        zp[l2]    = z;
        inv[l2]   = 1.0f / s;
    }
}

// out[oc][l] = sum_j deq(chunks[j][oc][l]). Pure streaming elementwise reduce.
__global__ __launch_bounds__(256) void quant_reduce(
    const float* __restrict__ planes,
    const float* __restrict__ scale, const float* __restrict__ zp,
    const float* __restrict__ inv, float* __restrict__ out)
{
    const int e = blockIdx.x * 256 + threadIdx.x;   // 512 blocks, e < 131072
    const int l = e & (L_ - 1);
    const float sc = scale[l], zv = zp[l], iv = inv[l];
    float s = 0.f;
#pragma unroll 4
    for (int j = 0; j < NCH; j++) {
        const float a  = planes[j * PLANE_ + e];
        float       qn = rintf(a * iv) + zv;        // rintf == round-half-even
        qn = fminf(fmaxf(qn, 0.f), QMAX_);
        s += (qn - zv) * sc;
    }
    out[e] = s;
}

// ---- fallback path (tiny ws): round-3 style fused 2-pass, ~3 MB ws ----
template <bool QUANT>
__global__ __launch_bounds__(256) void cas_direct(
    const float* __restrict__ xpad, const float* __restrict__ w,
    float* __restrict__ out, const float* __restrict__ scale,
    const float* __restrict__ zp, const float* __restrict__ inv)
{
    const int t = threadIdx.x;
    const int ocBase = blockIdx.x * 16;
    const int l = blockIdx.y * 256 + t;
    const int oh = l >> 5, ow = l & 31;
    const int lane_off = oh * 34 + ow;

    float sc = 0.f, zv = 0.f, iv = 0.f;
    if (QUANT) { sc = scale[l]; zv = zp[l]; iv = inv[l]; }

    float acc[16];
#pragma unroll
    for (int oc = 0; oc < 16; oc++) acc[oc] = 0.f;

    for (int j = 0; j < NCH; j++) {
        const int d0 = j * 32;
        float xv[32];
#pragma unroll
        for (int dd = 0; dd < 32; dd++) {
            const int d = d0 + dd, c = d / 9, r = d - 9 * c;
            const int kh = r / 3, kw = r - 3 * kh;
            xv[dd] = xpad[c * 1156 + kh * 34 + kw + lane_off];
        }
#pragma unroll
        for (int oc = 0; oc < 16; oc++) {
            const float4* wp = (const float4*)(w + (ocBase + oc) * CKK_ + d0);
            float pa = 0.f, pb = 0.f;
#pragma unroll
            for (int k4 = 0; k4 < 8; k4++) {
                const float4 wv = wp[k4];
                float& pr = (k4 < 4) ? pa : pb;
                pr = fmaf(wv.x, xv[4 * k4 + 0], pr);
                pr = fmaf(wv.y, xv[4 * k4 + 1], pr);
                pr = fmaf(wv.z, xv[4 * k4 + 2], pr);
                pr = fmaf(wv.w, xv[4 * k4 + 3], pr);
            }
            const float s2 = pa + pb;
            if (QUANT) {
                float qn = rintf(s2 * iv) + zv;
                qn = fminf(fmaxf(qn, 0.f), QMAX_);
                acc[oc] += (qn - zv) * sc;
            } else {
                acc[oc] += s2;
            }
        }
    }
#pragma unroll
    for (int oc = 0; oc < 16; oc++)
        out[(ocBase + oc) * L_ + l] = acc[oc];
}

__global__ __launch_bounds__(256) void minmax_conv(
    const float* __restrict__ conv, const float* __restrict__ bias,
    float* __restrict__ scale, float* __restrict__ zp, float* __restrict__ inv)
{
    __shared__ float smn[16][17], smx[16][17];
    const int t = threadIdx.x, li = t & 15, g = t >> 4;
    const int l = blockIdx.x * 16 + li;
    float mn = INFINITY, mx = -INFINITY;
#pragma unroll
    for (int i = 0; i < 8; i++) {
        const int oc = g * 8 + i;
        const float v = conv[oc * L_ + l] + bias[oc];
        mn = fminf(mn, v); mx = fmaxf(mx, v);
    }
    smn[g][li] = mn; smx[g][li] = mx;
    __syncthreads();
    if (t < 16) {
        const int l2 = blockIdx.x * 16 + t;
        float amn = smn[0][t], amx = smx[0][t];
#pragma unroll
        for (int g2 = 1; g2 < 16; g2++) {
            amn = fminf(amn, smn[g2][t]); amx = fmaxf(amx, smx[g2][t]);
        }
        const float s = (amx - amn) / QMAX_;
        float z = -amn / s;
        z = fminf(fmaxf(z, 0.f), QMAX_);
        z = truncf(z);
        scale[l2] = s; zp[l2] = z; inv[l2] = 1.0f / s;
    }
}

extern "C" void kernel_launch(void* const* d_in, const int* in_sizes, int n_in,
                              void* d_out, int out_size, void* d_ws, size_t ws_size,
                              hipStream_t stream) {
    const float* x    = (const float*)d_in[0];  // 128*32*32
    const float* w    = (const float*)d_in[1];  // 128*1152
    const float* bias = (const float*)d_in[2];  // 128
    float* out = (float*)d_out;                 // 128*1024
    float* ws  = (float*)d_ws;

    const size_t main_need = ((size_t)NCH * PLANE_ + 3 * 1024 + XPAD_N) * 4;
    if (ws_size >= main_need) {
        float* planes = ws;                       // 36 * 131072
        float* scale  = planes + (size_t)NCH * PLANE_;
        float* zpv    = scale + 1024;
        float* inv    = zpv + 1024;
        float* xpad   = inv + 1024;

        pad_x<<<(XPAD_N + 255) / 256, 256, 0, stream>>>(x, xpad);
        gemm_chunks<<<dim3(16, 4, NCH), 256, 0, stream>>>(xpad, w, planes);
        minmax_planes<<<64, 256, 0, stream>>>(planes, bias, scale, zpv, inv);
        quant_reduce<<<512, 256, 0, stream>>>(planes, scale, zpv, inv, out);
    } else {
        // small-ws fallback: fused two-pass (round-3 structure)
        float* conv  = ws;                        // 131072
        float* scale = conv + PLANE_;
        float* zpv   = scale + 1024;
        float* inv   = zpv + 1024;
        float* xpad  = inv + 1024;

        pad_x<<<(XPAD_N + 255) / 256, 256, 0, stream>>>(x, xpad);
        cas_direct<false><<<dim3(8, 4), 256, 0, stream>>>(xpad, w, conv, nullptr, nullptr, nullptr);
        minmax_conv<<<64, 256, 0, stream>>>(conv, bias, scale, zpv, inv);
        cas_direct<true><<<dim3(8, 4), 256, 0, stream>>>(xpad, w, out, scale, zpv, inv);
    }
}

// Round 5
// 92.238 us; speedup vs baseline: 1.5132x; 1.1969x over previous
//
#include <hip/hip_runtime.h>

// casConv2d: B=1, C=128, H=W=32, OC=128, K=3, pad=1, stride=1.
// L = 1024, CKK = 1152 = 36 exact 32-tap chunks (reference front-pad chunk == 0).
//
// Round-5. Round-4 counters showed the harness's 268 MB ws re-poison fill
// (~46 us) inside the timed window as a fixed floor; of the remaining ~60 us,
// the [j][oc][l] plane layout made minmax (64 blocks, 1 wave/SIMD, 288 loads
// @512KB stride, 1/4-coalesced) and quant_reduce latency-bound. Fixes:
//   1. planes stored [j][l][oc] (oc minor) -> minmax/quant reads are fully
//      coalesced 256 B/wave.
//   2. minmax: 1024 blocks (1 pixel each, 16 waves/CU), 18 coalesced loads
//      per thread, LDS tree over 128 oc.
//   3. pad_x dropped: unpadded tap addr = uniform(d) + l, so padding is 2
//      compares + 2 cndmasks per tap inline in the gemm (one fewer dispatch).
#define L_     1024
#define CKK_   1152
#define QMAX_  255.0f
#define NCH    36
#define PLANE_ 131072         // 128*1024 floats per chunk plane

// One 32-tap chunk sum per (oc,l). Tile: 8 oc x 256 l x 1 chunk.
// grid = (16 ocg, 4 lg, 36) = 2304 blocks = 36 waves/CU (round-4 winner).
// Stores planes[j][l][oc] (oc minor).
__global__ __launch_bounds__(256) void gemm_chunks(
    const float* __restrict__ x,      // [128][32][32] (unpadded)
    const float* __restrict__ w,      // [128][1152]
    float* __restrict__ planes)       // [36][1024][128]
{
    const int t      = threadIdx.x;
    const int ocBase = blockIdx.x * 8;
    const int l      = blockIdx.y * 256 + t;
    const int j      = blockIdx.z;
    const int oh     = l >> 5, ow = l & 31;
    const int d0     = j * 32;

    // x-column: 32 independent loads. Tap decode is wave-uniform (scalar pipe);
    // per-lane cost is 2 cmp + 2 cndmask for the implicit zero-padding.
    float xv[32];
#pragma unroll
    for (int dd = 0; dd < 32; dd++) {
        const int d  = d0 + dd;                 // uniform
        const int c  = d / 9;
        const int r  = d - 9 * c;
        const int kh = r / 3;
        const int kw = r - 3 * kh;
        const int off = c * 1024 + (kh - 1) * 32 + (kw - 1);  // uniform
        const bool ok = ((unsigned)(oh + kh - 1) < 32u) &
                        ((unsigned)(ow + kw - 1) < 32u);
        const int idx = ok ? (off + l) : 0;     // clamp OOB lanes to x[0]
        const float vv = x[idx];
        xv[dd] = ok ? vv : 0.f;
    }

    float acc[8];
#pragma unroll
    for (int oc = 0; oc < 8; oc++) {
        // wave-uniform W row -> s_load into SGPRs (constant cache)
        const float4* wp = (const float4*)(w + (ocBase + oc) * CKK_ + d0);
        float pa = 0.f, pb = 0.f;               // two chains hide FMA latency
#pragma unroll
        for (int k4 = 0; k4 < 4; k4++) {
            const float4 wv = wp[k4];
            pa = fmaf(wv.x, xv[4 * k4 + 0], pa);
            pa = fmaf(wv.y, xv[4 * k4 + 1], pa);
            pa = fmaf(wv.z, xv[4 * k4 + 2], pa);
            pa = fmaf(wv.w, xv[4 * k4 + 3], pa);
        }
#pragma unroll
        for (int k4 = 4; k4 < 8; k4++) {
            const float4 wv = wp[k4];
            pb = fmaf(wv.x, xv[4 * k4 + 0], pb);
            pb = fmaf(wv.y, xv[4 * k4 + 1], pb);
            pb = fmaf(wv.z, xv[4 * k4 + 2], pb);
            pb = fmaf(wv.w, xv[4 * k4 + 3], pb);
        }
        acc[oc] = pa + pb;
    }

    // planes[j][l][ocBase..ocBase+8]: two float4 stores per thread.
    float* dst = planes + (size_t)j * PLANE_ + (size_t)l * 128 + ocBase;
    *(float4*)(dst + 0) = make_float4(acc[0], acc[1], acc[2], acc[3]);
    *(float4*)(dst + 4) = make_float4(acc[4], acc[5], acc[6], acc[7]);
}

// Per-pixel min/max over 128 oc of (sum_j chunks + bias) -> scale, zp, inv.
// 1024 blocks (one pixel each, 16 waves/CU). Thread (oc = t&127, j-half = t>>7)
// does 18 fully-coalesced loads (lanes span contiguous oc); LDS tree over oc.
__global__ __launch_bounds__(256) void minmax_t(
    const float* __restrict__ planes,  // [36][1024][128]
    const float* __restrict__ bias,    // [128]
    float* __restrict__ scale, float* __restrict__ zp, float* __restrict__ inv)
{
    __shared__ float part[256];
    __shared__ float mnb[128], mxb[128];
    const int t  = threadIdx.x;
    const int oc = t & 127, jh = t >> 7;
    const int l  = blockIdx.x;

    const float* p = planes + (size_t)(jh * 18) * PLANE_ + (size_t)l * 128 + oc;
    float s = 0.f;
#pragma unroll
    for (int j = 0; j < 18; j++) s += p[(size_t)j * PLANE_];
    part[t] = s;
    __syncthreads();

    if (t < 128) {
        const float tot = part[t] + part[t + 128] + bias[t];
        mnb[t] = tot;
        mxb[t] = tot;
    }
    __syncthreads();
#pragma unroll
    for (int st = 64; st > 0; st >>= 1) {
        if (t < st) {
            mnb[t] = fminf(mnb[t], mnb[t + st]);
            mxb[t] = fmaxf(mxb[t], mxb[t + st]);
        }
        __syncthreads();
    }
    if (t == 0) {
        const float amn = mnb[0], amx = mxb[0];
        const float sv  = (amx - amn) / QMAX_;
        float z = -amn / sv;
        z = fmaxf(z, 0.f);          // fmaxf(NaN,0)=0 matches where(isnan, 0)
        z = fminf(z, QMAX_);
        z = truncf(z);
        scale[l] = sv;
        zp[l]    = z;
        inv[l]   = 1.0f / sv;
    }
}

// out[oc][l] = sum_j deq(planes[j][l][oc]). 512 blocks; reads fully coalesced
// (lanes span contiguous oc); scale/zp/inv are wave-uniform scalar loads.
__global__ __launch_bounds__(256) void quant_t(
    const float* __restrict__ planes,
    const float* __restrict__ scale, const float* __restrict__ zp,
    const float* __restrict__ inv, float* __restrict__ out)
{
    const int e  = blockIdx.x * 256 + threadIdx.x;  // < 131072
    const int oc = e & 127, l = e >> 7;
    const float sc = scale[l], zv = zp[l], iv = inv[l];
    float s = 0.f;
#pragma unroll 6
    for (int j = 0; j < NCH; j++) {
        const float a  = planes[(size_t)j * PLANE_ + e];
        float       qn = rintf(a * iv) + zv;        // rintf == round-half-even
        qn = fminf(fmaxf(qn, 0.f), QMAX_);
        s += (qn - zv) * sc;
    }
    out[oc * L_ + l] = s;   // 512 KB of strided dwords; L2 absorbs
}

// ---- small-ws fallback: fused two-pass, ~520 KB ws (inline padding) ----
template <bool QUANT>
__global__ __launch_bounds__(256) void cas_direct(
    const float* __restrict__ x, const float* __restrict__ w,
    float* __restrict__ out, const float* __restrict__ scale,
    const float* __restrict__ zp, const float* __restrict__ inv)
{
    const int t = threadIdx.x;
    const int ocBase = blockIdx.x * 16;
    const int l = blockIdx.y * 256 + t;
    const int oh = l >> 5, ow = l & 31;

    float sc = 0.f, zv = 0.f, iv = 0.f;
    if (QUANT) { sc = scale[l]; zv = zp[l]; iv = inv[l]; }

    float acc[16];
#pragma unroll
    for (int oc = 0; oc < 16; oc++) acc[oc] = 0.f;

    for (int j = 0; j < NCH; j++) {
        const int d0 = j * 32;
        float xv[32];
#pragma unroll
        for (int dd = 0; dd < 32; dd++) {
            const int d = d0 + dd, c = d / 9, r = d - 9 * c;
            const int kh = r / 3, kw = r - 3 * kh;
            const int off = c * 1024 + (kh - 1) * 32 + (kw - 1);
            const bool ok = ((unsigned)(oh + kh - 1) < 32u) &
                            ((unsigned)(ow + kw - 1) < 32u);
            const int idx = ok ? (off + l) : 0;
            const float vv = x[idx];
            xv[dd] = ok ? vv : 0.f;
        }
#pragma unroll
        for (int oc = 0; oc < 16; oc++) {
            const float4* wp = (const float4*)(w + (ocBase + oc) * CKK_ + d0);
            float pa = 0.f, pb = 0.f;
#pragma unroll
            for (int k4 = 0; k4 < 8; k4++) {
                const float4 wv = wp[k4];
                float& pr = (k4 < 4) ? pa : pb;
                pr = fmaf(wv.x, xv[4 * k4 + 0], pr);
                pr = fmaf(wv.y, xv[4 * k4 + 1], pr);
                pr = fmaf(wv.z, xv[4 * k4 + 2], pr);
                pr = fmaf(wv.w, xv[4 * k4 + 3], pr);
            }
            const float s2 = pa + pb;
            if (QUANT) {
                float qn = rintf(s2 * iv) + zv;
                qn = fminf(fmaxf(qn, 0.f), QMAX_);
                acc[oc] += (qn - zv) * sc;
            } else {
                acc[oc] += s2;
            }
        }
    }
#pragma unroll
    for (int oc = 0; oc < 16; oc++)
        out[(ocBase + oc) * L_ + l] = acc[oc];
}

__global__ __launch_bounds__(256) void minmax_conv(
    const float* __restrict__ conv, const float* __restrict__ bias,
    float* __restrict__ scale, float* __restrict__ zp, float* __restrict__ inv)
{
    __shared__ float smn[16][17], smx[16][17];
    const int t = threadIdx.x, li = t & 15, g = t >> 4;
    const int l = blockIdx.x * 16 + li;
    float mn = INFINITY, mx = -INFINITY;
#pragma unroll
    for (int i = 0; i < 8; i++) {
        const int oc = g * 8 + i;
        const float v = conv[oc * L_ + l] + bias[oc];
        mn = fminf(mn, v); mx = fmaxf(mx, v);
    }
    smn[g][li] = mn; smx[g][li] = mx;
    __syncthreads();
    if (t < 16) {
        const int l2 = blockIdx.x * 16 + t;
        float amn = smn[0][t], amx = smx[0][t];
#pragma unroll
        for (int g2 = 1; g2 < 16; g2++) {
            amn = fminf(amn, smn[g2][t]); amx = fmaxf(amx, smx[g2][t]);
        }
        const float s = (amx - amn) / QMAX_;
        float z = -amn / s;
        z = fminf(fmaxf(z, 0.f), QMAX_);
        z = truncf(z);
        scale[l2] = s; zp[l2] = z; inv[l2] = 1.0f / s;
    }
}

extern "C" void kernel_launch(void* const* d_in, const int* in_sizes, int n_in,
                              void* d_out, int out_size, void* d_ws, size_t ws_size,
                              hipStream_t stream) {
    const float* x    = (const float*)d_in[0];  // 128*32*32
    const float* w    = (const float*)d_in[1];  // 128*1152
    const float* bias = (const float*)d_in[2];  // 128
    float* out = (float*)d_out;                 // 128*1024
    float* ws  = (float*)d_ws;

    const size_t main_need = ((size_t)NCH * PLANE_ + 3 * 1024) * 4;
    if (ws_size >= main_need) {
        float* planes = ws;                       // 36 * 131072, [j][l][oc]
        float* scale  = planes + (size_t)NCH * PLANE_;
        float* zpv    = scale + 1024;
        float* inv    = zpv + 1024;

        gemm_chunks<<<dim3(16, 4, NCH), 256, 0, stream>>>(x, w, planes);
        minmax_t<<<1024, 256, 0, stream>>>(planes, bias, scale, zpv, inv);
        quant_t<<<512, 256, 0, stream>>>(planes, scale, zpv, inv, out);
    } else {
        float* conv  = ws;                        // 131072
        float* scale = conv + PLANE_;
        float* zpv   = scale + 1024;
        float* inv   = zpv + 1024;

        cas_direct<false><<<dim3(8, 4), 256, 0, stream>>>(x, w, conv, nullptr, nullptr, nullptr);
        minmax_conv<<<64, 256, 0, stream>>>(conv, bias, scale, zpv, inv);
        cas_direct<true><<<dim3(8, 4), 256, 0, stream>>>(x, w, out, scale, zpv, inv);
    }
}

// Round 6
// 82.378 us; speedup vs baseline: 1.6943x; 1.1197x over previous
//
#include <hip/hip_runtime.h>

// casConv2d: B=1, C=128, H=W=32, OC=128, K=3, pad=1, stride=1.
// L = 1024, CKK = 1152 = 36 exact 32-tap chunks (reference front-pad chunk == 0).
//
// Round-6. Cross-round subtraction pinned the gemm at ~39 us (vs ~2 us FMA
// floor): W rows (8 oc x 32 f = 256 SGPRs) blow the ~102-SGPR budget, so the
// compiler serializes s_load -> waitcnt -> FMA in ~700-cyc batches. Fixes:
//   1. W staged through LDS (1 KB/block, one coalesced dword per thread,
//      issued BEFORE the x loads so ds_write waits vmcnt(32) with x still in
//      flight); compute reads W via ds_read_b128 broadcast (uniform addr =
//      conflict-free, pipelined, zero SGPR pressure).
//   2. minmax+quant fused: plane values stay in VGPRs across the scale
//      reduction -> planes read once (18 MB), one dispatch and all
//      scale/zp/inv traffic eliminated.
#define L_     1024
#define CKK_   1152
#define QMAX_  255.0f
#define NCH    36
#define PLANE_ 131072         // 128*1024 floats per chunk plane

// One 32-tap chunk sum per (oc,l). Tile: 8 oc x 256 l x 1 chunk.
// grid = (16 ocg, 4 lg, 36) = 2304 blocks = 36 waves/CU.
__global__ __launch_bounds__(256) void gemm_chunks(
    const float* __restrict__ x,      // [128][32][32]
    const float* __restrict__ w,      // [128][1152]
    float* __restrict__ planes)       // [36][1024][128] (oc minor)
{
    __shared__ __align__(16) float Ws[8][32];   // [oc][tap], 1 KB
    const int t      = threadIdx.x;
    const int ocBase = blockIdx.x * 8;
    const int l      = blockIdx.y * 256 + t;
    const int j      = blockIdx.z;
    const int oh     = l >> 5, ow = l & 31;
    const int d0     = j * 32;

    // W staging load FIRST (one coalesced dword per thread: 8 oc x 32 taps).
    const int  s_oc = t >> 5, s_k = t & 31;
    const float wval = w[(ocBase + s_oc) * CKK_ + d0 + s_k];

    // x-column: 32 independent loads (tap decode wave-uniform -> scalar pipe;
    // implicit zero-pad = 2 cmp + 2 cndmask per tap). All 32 stay in flight.
    float xv[32];
#pragma unroll
    for (int dd = 0; dd < 32; dd++) {
        const int d  = d0 + dd;
        const int c  = d / 9;
        const int r  = d - 9 * c;
        const int kh = r / 3;
        const int kw = r - 3 * kh;
        const int off = c * 1024 + (kh - 1) * 32 + (kw - 1);   // uniform
        const bool ok = ((unsigned)(oh + kh - 1) < 32u) &
                        ((unsigned)(ow + kw - 1) < 32u);
        const int idx = ok ? (off + l) : 0;
        const float vv = x[idx];
        xv[dd] = ok ? vv : 0.f;
    }

    Ws[s_oc][s_k] = wval;     // ds_write waits only for the W load (vmcnt(32))
    __syncthreads();

    float acc[8];
#pragma unroll
    for (int oc = 0; oc < 8; oc++) {
        const float4* wp = (const float4*)&Ws[oc][0];  // uniform -> broadcast
        float pa = 0.f, pb = 0.f;                      // two chains for ILP
#pragma unroll
        for (int k4 = 0; k4 < 4; k4++) {
            const float4 wv = wp[k4];
            pa = fmaf(wv.x, xv[4 * k4 + 0], pa);
            pa = fmaf(wv.y, xv[4 * k4 + 1], pa);
            pa = fmaf(wv.z, xv[4 * k4 + 2], pa);
            pa = fmaf(wv.w, xv[4 * k4 + 3], pa);
        }
#pragma unroll
        for (int k4 = 4; k4 < 8; k4++) {
            const float4 wv = wp[k4];
            pb = fmaf(wv.x, xv[4 * k4 + 0], pb);
            pb = fmaf(wv.y, xv[4 * k4 + 1], pb);
            pb = fmaf(wv.z, xv[4 * k4 + 2], pb);
            pb = fmaf(wv.w, xv[4 * k4 + 3], pb);
        }
        acc[oc] = pa + pb;
    }

    float* dst = planes + (size_t)j * PLANE_ + (size_t)l * 128 + ocBase;
    *(float4*)(dst + 0) = make_float4(acc[0], acc[1], acc[2], acc[3]);
    *(float4*)(dst + 4) = make_float4(acc[4], acc[5], acc[6], acc[7]);
}

// Fused: per-pixel scale/zp from sum over chunks, then per-chunk fake-quant
// deq sum -> out. One block per pixel (1024 blocks, 16 waves/CU). Thread
// (oc = t&127, jh = t>>7) keeps its 18 plane values in VGPRs throughout.
__global__ __launch_bounds__(256) void fused_mq(
    const float* __restrict__ planes,  // [36][1024][128]
    const float* __restrict__ bias,    // [128]
    float* __restrict__ out)           // [128][1024]
{
    __shared__ float part[256];
    __shared__ float mnb[128], mxb[128];
    __shared__ float s_sc, s_zp, s_iv;
    const int t  = threadIdx.x;
    const int oc = t & 127, jh = t >> 7;
    const int l  = blockIdx.x;

    // 18 fully-coalesced loads (lanes span contiguous oc), all in flight.
    const float* p = planes + (size_t)(jh * 18) * PLANE_ + (size_t)l * 128 + oc;
    float v[18];
#pragma unroll
    for (int j = 0; j < 18; j++) v[j] = p[(size_t)j * PLANE_];

    float s = 0.f;
#pragma unroll
    for (int j = 0; j < 18; j++) s += v[j];
    part[t] = s;
    __syncthreads();

    if (t < 128) {
        const float tot = part[t] + part[t + 128] + bias[t];
        mnb[t] = tot;
        mxb[t] = tot;
    }
    __syncthreads();
#pragma unroll
    for (int st = 64; st > 0; st >>= 1) {
        if (t < st) {
            mnb[t] = fminf(mnb[t], mnb[t + st]);
            mxb[t] = fmaxf(mxb[t], mxb[t + st]);
        }
        __syncthreads();
    }
    if (t == 0) {
        const float amn = mnb[0], amx = mxb[0];
        const float sv  = (amx - amn) / QMAX_;
        float z = -amn / sv;
        z = fmaxf(z, 0.f);          // fmaxf(NaN,0)=0 matches where(isnan, 0)
        z = fminf(z, QMAX_);
        z = truncf(z);
        s_sc = sv;
        s_zp = z;
        s_iv = 1.0f / sv;
    }
    __syncthreads();

    const float sc = s_sc, zv = s_zp, iv = s_iv;
    float q = 0.f;
#pragma unroll
    for (int j = 0; j < 18; j++) {
        float qn = rintf(v[j] * iv) + zv;   // rintf == round-half-even
        qn = fminf(fmaxf(qn, 0.f), QMAX_);
        q += (qn - zv) * sc;
    }
    part[t] = q;
    __syncthreads();

    if (t < 128)
        out[oc * L_ + l] = part[t] + part[t + 128];
}

// ---- small-ws fallback (~520 KB): round-5 fused two-pass, known-correct ----
template <bool QUANT>
__global__ __launch_bounds__(256) void cas_direct(
    const float* __restrict__ x, const float* __restrict__ w,
    float* __restrict__ out, const float* __restrict__ scale,
    const float* __restrict__ zp, const float* __restrict__ inv)
{
    const int t = threadIdx.x;
    const int ocBase = blockIdx.x * 16;
    const int l = blockIdx.y * 256 + t;
    const int oh = l >> 5, ow = l & 31;

    float sc = 0.f, zv = 0.f, iv = 0.f;
    if (QUANT) { sc = scale[l]; zv = zp[l]; iv = inv[l]; }

    float acc[16];
#pragma unroll
    for (int oc = 0; oc < 16; oc++) acc[oc] = 0.f;

    for (int j = 0; j < NCH; j++) {
        const int d0 = j * 32;
        float xv[32];
#pragma unroll
        for (int dd = 0; dd < 32; dd++) {
            const int d = d0 + dd, c = d / 9, r = d - 9 * c;
            const int kh = r / 3, kw = r - 3 * kh;
            const int off = c * 1024 + (kh - 1) * 32 + (kw - 1);
            const bool ok = ((unsigned)(oh + kh - 1) < 32u) &
                            ((unsigned)(ow + kw - 1) < 32u);
            const int idx = ok ? (off + l) : 0;
            const float vv = x[idx];
            xv[dd] = ok ? vv : 0.f;
        }
#pragma unroll
        for (int oc = 0; oc < 16; oc++) {
            const float4* wp = (const float4*)(w + (ocBase + oc) * CKK_ + d0);
            float pa = 0.f, pb = 0.f;
#pragma unroll
            for (int k4 = 0; k4 < 8; k4++) {
                const float4 wv = wp[k4];
                float& pr = (k4 < 4) ? pa : pb;
                pr = fmaf(wv.x, xv[4 * k4 + 0], pr);
                pr = fmaf(wv.y, xv[4 * k4 + 1], pr);
                pr = fmaf(wv.z, xv[4 * k4 + 2], pr);
                pr = fmaf(wv.w, xv[4 * k4 + 3], pr);
            }
            const float s2 = pa + pb;
            if (QUANT) {
                float qn = rintf(s2 * iv) + zv;
                qn = fminf(fmaxf(qn, 0.f), QMAX_);
                acc[oc] += (qn - zv) * sc;
            } else {
                acc[oc] += s2;
            }
        }
    }
#pragma unroll
    for (int oc = 0; oc < 16; oc++)
        out[(ocBase + oc) * L_ + l] = acc[oc];
}

__global__ __launch_bounds__(256) void minmax_conv(
    const float* __restrict__ conv, const float* __restrict__ bias,
    float* __restrict__ scale, float* __restrict__ zp, float* __restrict__ inv)
{
    __shared__ float smn[16][17], smx[16][17];
    const int t = threadIdx.x, li = t & 15, g = t >> 4;
    const int l = blockIdx.x * 16 + li;
    float mn = INFINITY, mx = -INFINITY;
#pragma unroll
    for (int i = 0; i < 8; i++) {
        const int oc = g * 8 + i;
        const float v = conv[oc * L_ + l] + bias[oc];
        mn = fminf(mn, v); mx = fmaxf(mx, v);
    }
    smn[g][li] = mn; smx[g][li] = mx;
    __syncthreads();
    if (t < 16) {
        const int l2 = blockIdx.x * 16 + t;
        float amn = smn[0][t], amx = smx[0][t];
#pragma unroll
        for (int g2 = 1; g2 < 16; g2++) {
            amn = fminf(amn, smn[g2][t]); amx = fmaxf(amx, smx[g2][t]);
        }
        const float s = (amx - amn) / QMAX_;
        float z = -amn / s;
        z = fminf(fmaxf(z, 0.f), QMAX_);
        z = truncf(z);
        scale[l2] = s; zp[l2] = z; inv[l2] = 1.0f / s;
    }
}

extern "C" void kernel_launch(void* const* d_in, const int* in_sizes, int n_in,
                              void* d_out, int out_size, void* d_ws, size_t ws_size,
                              hipStream_t stream) {
    const float* x    = (const float*)d_in[0];  // 128*32*32
    const float* w    = (const float*)d_in[1];  // 128*1152
    const float* bias = (const float*)d_in[2];  // 128
    float* out = (float*)d_out;                 // 128*1024
    float* ws  = (float*)d_ws;

    const size_t main_need = (size_t)NCH * PLANE_ * 4;
    if (ws_size >= main_need) {
        float* planes = ws;                     // 36 * 131072, [j][l][oc]
        gemm_chunks<<<dim3(16, 4, NCH), 256, 0, stream>>>(x, w, planes);
        fused_mq<<<1024, 256, 0, stream>>>(planes, bias, out);
    } else {
        float* conv  = ws;                      // 131072
        float* scale = conv + PLANE_;
        float* zpv   = scale + 1024;
        float* inv   = zpv + 1024;
        cas_direct<false><<<dim3(8, 4), 256, 0, stream>>>(x, w, conv, nullptr, nullptr, nullptr);
        minmax_conv<<<64, 256, 0, stream>>>(conv, bias, scale, zpv, inv);
        cas_direct<true><<<dim3(8, 4), 256, 0, stream>>>(x, w, out, scale, zpv, inv);
    }
}

// Round 7
// 75.918 us; speedup vs baseline: 1.8385x; 1.0851x over previous
//
#include <hip/hip_runtime.h>

// casConv2d: B=1, C=128, H=W=32, OC=128, K=3, pad=1, stride=1.
// L = 1024, CKK = 1152 = 36 exact 32-tap chunks (reference front-pad chunk == 0).
//
// Round-7. Region algebra (R5/R6) pins gemm at ~25-30 us vs ~5 us model even
// after the LDS-W fix. Diagnosis: [j][l][oc] stores from 8-oc blocks are 16B
// fragments at 512B lane stride; every 64B line is co-owned by 2 blocks ->
// L2 write-allocate RMW (reads ~19 MB before writing 19 MB). Fix: block owns
// ALL 128 oc x 64 px x 1 chunk -> epilogue writes full contiguous 512B lines
// per half-wave (zero partial lines). Also: 4ocx8px register microtile
// (1024 FMA/thread, FMA-bound) fed by W transposed [k][132] in LDS (b128
// reads at the 8-bank-cycle optimum) and x [k][64] (broadcast reads).
#define L_     1024
#define CKK_   1152
#define QMAX_  255.0f
#define NCH    36
#define PLANE_ 131072         // 128*1024 floats per chunk plane

// grid = (16 l-tiles of 64 px, 36 chunks) = 576 blocks, 256 threads.
__global__ __launch_bounds__(256) void gemm_chunks(
    const float* __restrict__ x,      // [128][32][32]
    const float* __restrict__ w,      // [128][1152]
    float* __restrict__ planes)       // [36][1024][128] (oc minor)
{
    __shared__ __align__(16) float Wb[32][132];  // [tap][oc], pad 132
    __shared__ __align__(16) float xs[32][64];   // [tap][l-local]

    const int t   = threadIdx.x;
    const int l0  = blockIdx.x * 64;             // 64 px = output rows oh0, oh0+1
    const int j   = blockIdx.y;
    const int d0  = j * 32;
    const int oh0 = l0 >> 5;

    // ---- stage W chunk (16 KB) : 4 float4 global loads per thread ----
    float4 wld[4];
    int    wo[4], wk[4];
#pragma unroll
    for (int it = 0; it < 4; it++) {
        const int f4 = it * 256 + t;             // 1024 float4s = 128 oc x 8
        wo[it]  = f4 >> 3;                       // oc
        wk[it]  = (f4 & 7) * 4;                  // tap base
        wld[it] = *(const float4*)(w + wo[it] * CKK_ + d0 + wk[it]);
    }

    // ---- stage x chunk (8 KB) : 8 predicated scalar loads per thread ----
    float xl[8];
    int   xk[8], xll[8];
#pragma unroll
    for (int it = 0; it < 8; it++) {
        const int e  = it * 256 + t;             // 2048 = 32 taps x 64 px
        const int k  = e >> 6, ll = e & 63;
        const int d  = d0 + k;                   // uniform tap id
        const int c  = d / 9, r = d - 9 * c;
        const int kh = r / 3, kw = r - 3 * kh;
        const int iy = oh0 + (ll >> 5) + kh - 1;
        const int ix = (ll & 31) + kw - 1;
        const bool ok = ((unsigned)iy < 32u) & ((unsigned)ix < 32u);
        const int idx = ok ? (c * 1024 + iy * 32 + ix) : 0;
        const float v = x[idx];
        xl[it] = ok ? v : 0.f;
        xk[it] = k; xll[it] = ll;
    }

    // LDS writes (W transposed: [k][oc]); <=4-way write aliasing, amortized.
#pragma unroll
    for (int it = 0; it < 4; it++) {
        Wb[wk[it] + 0][wo[it]] = wld[it].x;
        Wb[wk[it] + 1][wo[it]] = wld[it].y;
        Wb[wk[it] + 2][wo[it]] = wld[it].z;
        Wb[wk[it] + 3][wo[it]] = wld[it].w;
    }
#pragma unroll
    for (int it = 0; it < 8; it++)
        xs[xk[it]][xll[it]] = xl[it];
    __syncthreads();

    // ---- compute: 4 oc x 8 px per thread, 1024 FMA, 32 indep chains ----
    const int oc0 = (t & 31) * 4;
    const int ll0 = (t >> 5) * 8;
    float acc[4][8];
#pragma unroll
    for (int r = 0; r < 4; r++)
#pragma unroll
        for (int i = 0; i < 8; i++) acc[r][i] = 0.f;

#pragma unroll
    for (int k = 0; k < 32; k++) {
        const float4 wv = *(const float4*)&Wb[k][oc0];      // 8-bank-cyc optimum
        const float4 xa = *(const float4*)&xs[k][ll0];      // broadcast
        const float4 xb = *(const float4*)&xs[k][ll0 + 4];  // broadcast
        acc[0][0] = fmaf(wv.x, xa.x, acc[0][0]);
        acc[0][1] = fmaf(wv.x, xa.y, acc[0][1]);
        acc[0][2] = fmaf(wv.x, xa.z, acc[0][2]);
        acc[0][3] = fmaf(wv.x, xa.w, acc[0][3]);
        acc[0][4] = fmaf(wv.x, xb.x, acc[0][4]);
        acc[0][5] = fmaf(wv.x, xb.y, acc[0][5]);
        acc[0][6] = fmaf(wv.x, xb.z, acc[0][6]);
        acc[0][7] = fmaf(wv.x, xb.w, acc[0][7]);
        acc[1][0] = fmaf(wv.y, xa.x, acc[1][0]);
        acc[1][1] = fmaf(wv.y, xa.y, acc[1][1]);
        acc[1][2] = fmaf(wv.y, xa.z, acc[1][2]);
        acc[1][3] = fmaf(wv.y, xa.w, acc[1][3]);
        acc[1][4] = fmaf(wv.y, xb.x, acc[1][4]);
        acc[1][5] = fmaf(wv.y, xb.y, acc[1][5]);
        acc[1][6] = fmaf(wv.y, xb.z, acc[1][6]);
        acc[1][7] = fmaf(wv.y, xb.w, acc[1][7]);
        acc[2][0] = fmaf(wv.z, xa.x, acc[2][0]);
        acc[2][1] = fmaf(wv.z, xa.y, acc[2][1]);
        acc[2][2] = fmaf(wv.z, xa.z, acc[2][2]);
        acc[2][3] = fmaf(wv.z, xa.w, acc[2][3]);
        acc[2][4] = fmaf(wv.z, xb.x, acc[2][4]);
        acc[2][5] = fmaf(wv.z, xb.y, acc[2][5]);
        acc[2][6] = fmaf(wv.z, xb.z, acc[2][6]);
        acc[2][7] = fmaf(wv.z, xb.w, acc[2][7]);
        acc[3][0] = fmaf(wv.w, xa.x, acc[3][0]);
        acc[3][1] = fmaf(wv.w, xa.y, acc[3][1]);
        acc[3][2] = fmaf(wv.w, xa.z, acc[3][2]);
        acc[3][3] = fmaf(wv.w, xa.w, acc[3][3]);
        acc[3][4] = fmaf(wv.w, xb.x, acc[3][4]);
        acc[3][5] = fmaf(wv.w, xb.y, acc[3][5]);
        acc[3][6] = fmaf(wv.w, xb.z, acc[3][6]);
        acc[3][7] = fmaf(wv.w, xb.w, acc[3][7]);
    }

    // ---- epilogue: fully coalesced full-line stores ----
    // For each i: lanes 0..31 of a wave write one contiguous 512B pixel row.
    float* dst = planes + (size_t)j * PLANE_ + (size_t)l0 * 128;
#pragma unroll
    for (int i = 0; i < 8; i++)
        *(float4*)(dst + (ll0 + i) * 128 + oc0) =
            make_float4(acc[0][i], acc[1][i], acc[2][i], acc[3][i]);
}

// Fused minmax+quant (unchanged from R6): one block per pixel, 18 plane
// values per thread held in VGPRs across the scale reduction.
__global__ __launch_bounds__(256) void fused_mq(
    const float* __restrict__ planes,  // [36][1024][128]
    const float* __restrict__ bias,    // [128]
    float* __restrict__ out)           // [128][1024]
{
    __shared__ float part[256];
    __shared__ float mnb[128], mxb[128];
    __shared__ float s_sc, s_zp, s_iv;
    const int t  = threadIdx.x;
    const int oc = t & 127, jh = t >> 7;
    const int l  = blockIdx.x;

    const float* p = planes + (size_t)(jh * 18) * PLANE_ + (size_t)l * 128 + oc;
    float v[18];
#pragma unroll
    for (int j = 0; j < 18; j++) v[j] = p[(size_t)j * PLANE_];

    float s = 0.f;
#pragma unroll
    for (int j = 0; j < 18; j++) s += v[j];
    part[t] = s;
    __syncthreads();

    if (t < 128) {
        const float tot = part[t] + part[t + 128] + bias[t];
        mnb[t] = tot;
        mxb[t] = tot;
    }
    __syncthreads();
#pragma unroll
    for (int st = 64; st > 0; st >>= 1) {
        if (t < st) {
            mnb[t] = fminf(mnb[t], mnb[t + st]);
            mxb[t] = fmaxf(mxb[t], mxb[t + st]);
        }
        __syncthreads();
    }
    if (t == 0) {
        const float amn = mnb[0], amx = mxb[0];
        const float sv  = (amx - amn) / QMAX_;
        float z = -amn / sv;
        z = fmaxf(z, 0.f);          // fmaxf(NaN,0)=0 matches where(isnan, 0)
        z = fminf(z, QMAX_);
        z = truncf(z);
        s_sc = sv;
        s_zp = z;
        s_iv = 1.0f / sv;
    }
    __syncthreads();

    const float sc = s_sc, zv = s_zp, iv = s_iv;
    float q = 0.f;
#pragma unroll
    for (int j = 0; j < 18; j++) {
        float qn = rintf(v[j] * iv) + zv;   // rintf == round-half-even
        qn = fminf(fmaxf(qn, 0.f), QMAX_);
        q += (qn - zv) * sc;
    }
    part[t] = q;
    __syncthreads();

    if (t < 128)
        out[oc * L_ + l] = part[t] + part[t + 128];
}

// ---- small-ws fallback (~520 KB): known-correct two-pass ----
template <bool QUANT>
__global__ __launch_bounds__(256) void cas_direct(
    const float* __restrict__ x, const float* __restrict__ w,
    float* __restrict__ out, const float* __restrict__ scale,
    const float* __restrict__ zp, const float* __restrict__ inv)
{
    const int t = threadIdx.x;
    const int ocBase = blockIdx.x * 16;
    const int l = blockIdx.y * 256 + t;
    const int oh = l >> 5, ow = l & 31;

    float sc = 0.f, zv = 0.f, iv = 0.f;
    if (QUANT) { sc = scale[l]; zv = zp[l]; iv = inv[l]; }

    float acc[16];
#pragma unroll
    for (int oc = 0; oc < 16; oc++) acc[oc] = 0.f;

    for (int j = 0; j < NCH; j++) {
        const int d0 = j * 32;
        float xv[32];
#pragma unroll
        for (int dd = 0; dd < 32; dd++) {
            const int d = d0 + dd, c = d / 9, r = d - 9 * c;
            const int kh = r / 3, kw = r - 3 * kh;
            const int off = c * 1024 + (kh - 1) * 32 + (kw - 1);
            const bool ok = ((unsigned)(oh + kh - 1) < 32u) &
                            ((unsigned)(ow + kw - 1) < 32u);
            const int idx = ok ? (off + l) : 0;
            const float vv = x[idx];
            xv[dd] = ok ? vv : 0.f;
        }
#pragma unroll
        for (int oc = 0; oc < 16; oc++) {
            const float4* wp = (const float4*)(w + (ocBase + oc) * CKK_ + d0);
            float pa = 0.f, pb = 0.f;
#pragma unroll
            for (int k4 = 0; k4 < 8; k4++) {
                const float4 wv = wp[k4];
                float& pr = (k4 < 4) ? pa : pb;
                pr = fmaf(wv.x, xv[4 * k4 + 0], pr);
                pr = fmaf(wv.y, xv[4 * k4 + 1], pr);
                pr = fmaf(wv.z, xv[4 * k4 + 2], pr);
                pr = fmaf(wv.w, xv[4 * k4 + 3], pr);
            }
            const float s2 = pa + pb;
            if (QUANT) {
                float qn = rintf(s2 * iv) + zv;
                qn = fminf(fmaxf(qn, 0.f), QMAX_);
                acc[oc] += (qn - zv) * sc;
            } else {
                acc[oc] += s2;
            }
        }
    }
#pragma unroll
    for (int oc = 0; oc < 16; oc++)
        out[(ocBase + oc) * L_ + l] = acc[oc];
}

__global__ __launch_bounds__(256) void minmax_conv(
    const float* __restrict__ conv, const float* __restrict__ bias,
    float* __restrict__ scale, float* __restrict__ zp, float* __restrict__ inv)
{
    __shared__ float smn[16][17], smx[16][17];
    const int t = threadIdx.x, li = t & 15, g = t >> 4;
    const int l = blockIdx.x * 16 + li;
    float mn = INFINITY, mx = -INFINITY;
#pragma unroll
    for (int i = 0; i < 8; i++) {
        const int oc = g * 8 + i;
        const float v = conv[oc * L_ + l] + bias[oc];
        mn = fminf(mn, v); mx = fmaxf(mx, v);
    }
    smn[g][li] = mn; smx[g][li] = mx;
    __syncthreads();
    if (t < 16) {
        const int l2 = blockIdx.x * 16 + t;
        float amn = smn[0][t], amx = smx[0][t];
#pragma unroll
        for (int g2 = 1; g2 < 16; g2++) {
            amn = fminf(amn, smn[g2][t]); amx = fmaxf(amx, smx[g2][t]);
        }
        const float s = (amx - amn) / QMAX_;
        float z = -amn / s;
        z = fminf(fmaxf(z, 0.f), QMAX_);
        z = truncf(z);
        scale[l2] = s; zp[l2] = z; inv[l2] = 1.0f / s;
    }
}

extern "C" void kernel_launch(void* const* d_in, const int* in_sizes, int n_in,
                              void* d_out, int out_size, void* d_ws, size_t ws_size,
                              hipStream_t stream) {
    const float* x    = (const float*)d_in[0];  // 128*32*32
    const float* w    = (const float*)d_in[1];  // 128*1152
    const float* bias = (const float*)d_in[2];  // 128
    float* out = (float*)d_out;                 // 128*1024
    float* ws  = (float*)d_ws;

    const size_t main_need = (size_t)NCH * PLANE_ * 4;
    if (ws_size >= main_need) {
        float* planes = ws;                     // 36 * 131072, [j][l][oc]
        gemm_chunks<<<dim3(16, NCH), 256, 0, stream>>>(x, w, planes);
        fused_mq<<<1024, 256, 0, stream>>>(planes, bias, out);
    } else {
        float* conv  = ws;                      // 131072
        float* scale = conv + PLANE_;
        float* zpv   = scale + 1024;
        float* inv   = zpv + 1024;
        cas_direct<false><<<dim3(8, 4), 256, 0, stream>>>(x, w, conv, nullptr, nullptr, nullptr);
        minmax_conv<<<64, 256, 0, stream>>>(conv, bias, scale, zpv, inv);
        cas_direct<true><<<dim3(8, 4), 256, 0, stream>>>(x, w, out, scale, zpv, inv);
    }
}

// Round 8
// 74.768 us; speedup vs baseline: 1.8668x; 1.0154x over previous
//
#include <hip/hip_runtime.h>

// casConv2d: B=1, C=128, H=W=32, OC=128, K=3, pad=1, stride=1.
// L = 1024, CKK = 1152 = 36 exact 32-tap chunks (reference front-pad chunk == 0).
//
// Round-8. Budget algebra pins fused_mq at ~20-26 us (gemm is near its ~4 us
// floor after R7). Diagnosis: plane stride is exactly 512 KB, so each thread's
// 18 plane reads (and R5's 36) map to ONE L2 set (256 KB set period) ->
// 16-way set thrash, conflict misses, ~1 TB/s effective. Fix: pad plane
// stride by 256 B (PSTR = 131072 + 64 floats) so consecutive planes hit
// different sets. Numerically identical; one-line change producer+consumer.
#define L_     1024
#define CKK_   1152
#define QMAX_  255.0f
#define NCH    36
#define PSTR_  (131072 + 64)  // plane stride in floats: 512 KB + 256 B

// grid = (16 l-tiles of 64 px, 36 chunks) = 576 blocks, 256 threads.
// Block owns ALL 128 oc x 64 px x 1 chunk -> full-line coalesced stores.
__global__ __launch_bounds__(256) void gemm_chunks(
    const float* __restrict__ x,      // [128][32][32]
    const float* __restrict__ w,      // [128][1152]
    float* __restrict__ planes)       // [36][PSTR_] (payload [1024][128], oc minor)
{
    __shared__ __align__(16) float Wb[32][132];  // [tap][oc], pad 132
    __shared__ __align__(16) float xs[32][64];   // [tap][l-local]

    const int t   = threadIdx.x;
    const int l0  = blockIdx.x * 64;             // 64 px = output rows oh0, oh0+1
    const int j   = blockIdx.y;
    const int d0  = j * 32;
    const int oh0 = l0 >> 5;

    // ---- stage W chunk (16 KB): 4 float4 global loads per thread ----
    float4 wld[4];
    int    wo[4], wk[4];
#pragma unroll
    for (int it = 0; it < 4; it++) {
        const int f4 = it * 256 + t;             // 1024 float4s = 128 oc x 8
        wo[it]  = f4 >> 3;                       // oc
        wk[it]  = (f4 & 7) * 4;                  // tap base
        wld[it] = *(const float4*)(w + wo[it] * CKK_ + d0 + wk[it]);
    }

    // ---- stage x chunk (8 KB): 8 predicated scalar loads per thread ----
    float xl[8];
    int   xk[8], xll[8];
#pragma unroll
    for (int it = 0; it < 8; it++) {
        const int e  = it * 256 + t;             // 2048 = 32 taps x 64 px
        const int k  = e >> 6, ll = e & 63;
        const int d  = d0 + k;                   // uniform tap id
        const int c  = d / 9, r = d - 9 * c;
        const int kh = r / 3, kw = r - 3 * kh;
        const int iy = oh0 + (ll >> 5) + kh - 1;
        const int ix = (ll & 31) + kw - 1;
        const bool ok = ((unsigned)iy < 32u) & ((unsigned)ix < 32u);
        const int idx = ok ? (c * 1024 + iy * 32 + ix) : 0;
        const float v = x[idx];
        xl[it] = ok ? v : 0.f;
        xk[it] = k; xll[it] = ll;
    }

#pragma unroll
    for (int it = 0; it < 4; it++) {
        Wb[wk[it] + 0][wo[it]] = wld[it].x;
        Wb[wk[it] + 1][wo[it]] = wld[it].y;
        Wb[wk[it] + 2][wo[it]] = wld[it].z;
        Wb[wk[it] + 3][wo[it]] = wld[it].w;
    }
#pragma unroll
    for (int it = 0; it < 8; it++)
        xs[xk[it]][xll[it]] = xl[it];
    __syncthreads();

    // ---- compute: 4 oc x 8 px per thread, 1024 FMA, 32 indep chains ----
    const int oc0 = (t & 31) * 4;
    const int ll0 = (t >> 5) * 8;
    float acc[4][8];
#pragma unroll
    for (int r = 0; r < 4; r++)
#pragma unroll
        for (int i = 0; i < 8; i++) acc[r][i] = 0.f;

#pragma unroll
    for (int k = 0; k < 32; k++) {
        const float4 wv = *(const float4*)&Wb[k][oc0];
        const float4 xa = *(const float4*)&xs[k][ll0];
        const float4 xb = *(const float4*)&xs[k][ll0 + 4];
        acc[0][0] = fmaf(wv.x, xa.x, acc[0][0]);
        acc[0][1] = fmaf(wv.x, xa.y, acc[0][1]);
        acc[0][2] = fmaf(wv.x, xa.z, acc[0][2]);
        acc[0][3] = fmaf(wv.x, xa.w, acc[0][3]);
        acc[0][4] = fmaf(wv.x, xb.x, acc[0][4]);
        acc[0][5] = fmaf(wv.x, xb.y, acc[0][5]);
        acc[0][6] = fmaf(wv.x, xb.z, acc[0][6]);
        acc[0][7] = fmaf(wv.x, xb.w, acc[0][7]);
        acc[1][0] = fmaf(wv.y, xa.x, acc[1][0]);
        acc[1][1] = fmaf(wv.y, xa.y, acc[1][1]);
        acc[1][2] = fmaf(wv.y, xa.z, acc[1][2]);
        acc[1][3] = fmaf(wv.y, xa.w, acc[1][3]);
        acc[1][4] = fmaf(wv.y, xb.x, acc[1][4]);
        acc[1][5] = fmaf(wv.y, xb.y, acc[1][5]);
        acc[1][6] = fmaf(wv.y, xb.z, acc[1][6]);
        acc[1][7] = fmaf(wv.y, xb.w, acc[1][7]);
        acc[2][0] = fmaf(wv.z, xa.x, acc[2][0]);
        acc[2][1] = fmaf(wv.z, xa.y, acc[2][1]);
        acc[2][2] = fmaf(wv.z, xa.z, acc[2][2]);
        acc[2][3] = fmaf(wv.z, xa.w, acc[2][3]);
        acc[2][4] = fmaf(wv.z, xb.x, acc[2][4]);
        acc[2][5] = fmaf(wv.z, xb.y, acc[2][5]);
        acc[2][6] = fmaf(wv.z, xb.z, acc[2][6]);
        acc[2][7] = fmaf(wv.z, xb.w, acc[2][7]);
        acc[3][0] = fmaf(wv.w, xa.x, acc[3][0]);
        acc[3][1] = fmaf(wv.w, xa.y, acc[3][1]);
        acc[3][2] = fmaf(wv.w, xa.z, acc[3][2]);
        acc[3][3] = fmaf(wv.w, xa.w, acc[3][3]);
        acc[3][4] = fmaf(wv.w, xb.x, acc[3][4]);
        acc[3][5] = fmaf(wv.w, xb.y, acc[3][5]);
        acc[3][6] = fmaf(wv.w, xb.z, acc[3][6]);
        acc[3][7] = fmaf(wv.w, xb.w, acc[3][7]);
    }

    // ---- epilogue: full-line coalesced stores (512B per half-wave row) ----
    float* dst = planes + (size_t)j * PSTR_ + (size_t)l0 * 128;
#pragma unroll
    for (int i = 0; i < 8; i++)
        *(float4*)(dst + (ll0 + i) * 128 + oc0) =
            make_float4(acc[0][i], acc[1][i], acc[2][i], acc[3][i]);
}

// Fused minmax+quant: one block per pixel, 18 plane values per thread held
// in VGPRs across the scale reduction. Plane reads now at PSTR_ stride
// (set-conflict-free).
__global__ __launch_bounds__(256) void fused_mq(
    const float* __restrict__ planes,  // [36][PSTR_]
    const float* __restrict__ bias,    // [128]
    float* __restrict__ out)           // [128][1024]
{
    __shared__ float part[256];
    __shared__ float mnb[128], mxb[128];
    __shared__ float s_sc, s_zp, s_iv;
    const int t  = threadIdx.x;
    const int oc = t & 127, jh = t >> 7;
    const int l  = blockIdx.x;

    const float* p = planes + (size_t)(jh * 18) * PSTR_ + (size_t)l * 128 + oc;
    float v[18];
#pragma unroll
    for (int j = 0; j < 18; j++) v[j] = p[(size_t)j * PSTR_];

    float s = 0.f;
#pragma unroll
    for (int j = 0; j < 18; j++) s += v[j];
    part[t] = s;
    __syncthreads();

    if (t < 128) {
        const float tot = part[t] + part[t + 128] + bias[t];
        mnb[t] = tot;
        mxb[t] = tot;
    }
    __syncthreads();
#pragma unroll
    for (int st = 64; st > 0; st >>= 1) {
        if (t < st) {
            mnb[t] = fminf(mnb[t], mnb[t + st]);
            mxb[t] = fmaxf(mxb[t], mxb[t + st]);
        }
        __syncthreads();
    }
    if (t == 0) {
        const float amn = mnb[0], amx = mxb[0];
        const float sv  = (amx - amn) / QMAX_;
        float z = -amn / sv;
        z = fmaxf(z, 0.f);          // fmaxf(NaN,0)=0 matches where(isnan, 0)
        z = fminf(z, QMAX_);
        z = truncf(z);
        s_sc = sv;
        s_zp = z;
        s_iv = 1.0f / sv;
    }
    __syncthreads();

    const float sc = s_sc, zv = s_zp, iv = s_iv;
    float q = 0.f;
#pragma unroll
    for (int j = 0; j < 18; j++) {
        float qn = rintf(v[j] * iv) + zv;   // rintf == round-half-even
        qn = fminf(fmaxf(qn, 0.f), QMAX_);
        q += (qn - zv) * sc;
    }
    part[t] = q;
    __syncthreads();

    if (t < 128)
        out[oc * L_ + l] = part[t] + part[t + 128];
}

// ---- small-ws fallback (~520 KB): known-correct two-pass ----
template <bool QUANT>
__global__ __launch_bounds__(256) void cas_direct(
    const float* __restrict__ x, const float* __restrict__ w,
    float* __restrict__ out, const float* __restrict__ scale,
    const float* __restrict__ zp, const float* __restrict__ inv)
{
    const int t = threadIdx.x;
    const int ocBase = blockIdx.x * 16;
    const int l = blockIdx.y * 256 + t;
    const int oh = l >> 5, ow = l & 31;

    float sc = 0.f, zv = 0.f, iv = 0.f;
    if (QUANT) { sc = scale[l]; zv = zp[l]; iv = inv[l]; }

    float acc[16];
#pragma unroll
    for (int oc = 0; oc < 16; oc++) acc[oc] = 0.f;

    for (int j = 0; j < NCH; j++) {
        const int d0 = j * 32;
        float xv[32];
#pragma unroll
        for (int dd = 0; dd < 32; dd++) {
            const int d = d0 + dd, c = d / 9, r = d - 9 * c;
            const int kh = r / 3, kw = r - 3 * kh;
            const int off = c * 1024 + (kh - 1) * 32 + (kw - 1);
            const bool ok = ((unsigned)(oh + kh - 1) < 32u) &
                            ((unsigned)(ow + kw - 1) < 32u);
            const int idx = ok ? (off + l) : 0;
            const float vv = x[idx];
            xv[dd] = ok ? vv : 0.f;
        }
#pragma unroll
        for (int oc = 0; oc < 16; oc++) {
            const float4* wp = (const float4*)(w + (ocBase + oc) * CKK_ + d0);
            float pa = 0.f, pb = 0.f;
#pragma unroll
            for (int k4 = 0; k4 < 8; k4++) {
                const float4 wv = wp[k4];
                float& pr = (k4 < 4) ? pa : pb;
                pr = fmaf(wv.x, xv[4 * k4 + 0], pr);
                pr = fmaf(wv.y, xv[4 * k4 + 1], pr);
                pr = fmaf(wv.z, xv[4 * k4 + 2], pr);
                pr = fmaf(wv.w, xv[4 * k4 + 3], pr);
            }
            const float s2 = pa + pb;
            if (QUANT) {
                float qn = rintf(s2 * iv) + zv;
                qn = fminf(fmaxf(qn, 0.f), QMAX_);
                acc[oc] += (qn - zv) * sc;
            } else {
                acc[oc] += s2;
            }
        }
    }
#pragma unroll
    for (int oc = 0; oc < 16; oc++)
        out[(ocBase + oc) * L_ + l] = acc[oc];
}

__global__ __launch_bounds__(256) void minmax_conv(
    const float* __restrict__ conv, const float* __restrict__ bias,
    float* __restrict__ scale, float* __restrict__ zp, float* __restrict__ inv)
{
    __shared__ float smn[16][17], smx[16][17];
    const int t = threadIdx.x, li = t & 15, g = t >> 4;
    const int l = blockIdx.x * 16 + li;
    float mn = INFINITY, mx = -INFINITY;
#pragma unroll
    for (int i = 0; i < 8; i++) {
        const int oc = g * 8 + i;
        const float v = conv[oc * L_ + l] + bias[oc];
        mn = fminf(mn, v); mx = fmaxf(mx, v);
    }
    smn[g][li] = mn; smx[g][li] = mx;
    __syncthreads();
    if (t < 16) {
        const int l2 = blockIdx.x * 16 + t;
        float amn = smn[0][t], amx = smx[0][t];
#pragma unroll
        for (int g2 = 1; g2 < 16; g2++) {
            amn = fminf(amn, smn[g2][t]); amx = fmaxf(amx, smx[g2][t]);
        }
        const float s = (amx - amn) / QMAX_;
        float z = -amn / s;
        z = fminf(fmaxf(z, 0.f), QMAX_);
        z = truncf(z);
        scale[l2] = s; zp[l2] = z; inv[l2] = 1.0f / s;
    }
}

extern "C" void kernel_launch(void* const* d_in, const int* in_sizes, int n_in,
                              void* d_out, int out_size, void* d_ws, size_t ws_size,
                              hipStream_t stream) {
    const float* x    = (const float*)d_in[0];  // 128*32*32
    const float* w    = (const float*)d_in[1];  // 128*1152
    const float* bias = (const float*)d_in[2];  // 128
    float* out = (float*)d_out;                 // 128*1024
    float* ws  = (float*)d_ws;

    const size_t main_need = (size_t)NCH * PSTR_ * 4;
    if (ws_size >= main_need) {
        float* planes = ws;                     // 36 * PSTR_, [j][l][oc]
        gemm_chunks<<<dim3(16, NCH), 256, 0, stream>>>(x, w, planes);
        fused_mq<<<1024, 256, 0, stream>>>(planes, bias, out);
    } else {
        float* conv  = ws;                      // 131072
        float* scale = conv + 131072;
        float* zpv   = scale + 1024;
        float* inv   = zpv + 1024;
        cas_direct<false><<<dim3(8, 4), 256, 0, stream>>>(x, w, conv, nullptr, nullptr, nullptr);
        minmax_conv<<<64, 256, 0, stream>>>(conv, bias, scale, zpv, inv);
        cas_direct<true><<<dim3(8, 4), 256, 0, stream>>>(x, w, out, scale, zpv, inv);
    }
}